// Round 1
// baseline (451.856 us; speedup 1.0000x reference)
//
#include <hip/hip_runtime.h>

typedef _Float16 f16;
typedef _Float16 f16x4 __attribute__((ext_vector_type(4)));
typedef _Float16 f16x8 __attribute__((ext_vector_type(8)));
typedef float f32x4 __attribute__((ext_vector_type(4)));

// Problem constants (fixed by the reference)
#define NB 65536
#define SEQ 5
#define DM 128
#define NH 8
#define HDIM 16

// Pre-transposed f16 weights: [m][out_col][k], m: 0=Wq 1=Wk 2=Wv 3=Wo
__device__ __align__(16) f16 g_WT[4][128][128];

__global__ void k_wtrans(const float* __restrict__ Wq, const float* __restrict__ Wk,
                         const float* __restrict__ Wv, const float* __restrict__ Wo) {
    int tid = blockIdx.x * 256 + threadIdx.x;        // 65536 threads total
    int m = tid >> 14;
    int r = tid & 16383;
    int n = r >> 7;          // output column
    int k = r & 127;         // input (K) index
    const float* W = (m == 0) ? Wq : (m == 1) ? Wk : (m == 2) ? Wv : Wo;
    g_WT[m][n][k] = (f16)W[k * 128 + n];
}

// Fused QKV projection + attention + output projection.
// 320 threads = 5 waves; each workgroup owns 16 batches = 80 token rows = 5 MFMA row-tiles.
__global__ __launch_bounds__(320, 4)
void k_fused(const float* __restrict__ x, const float* __restrict__ bq,
             const float* __restrict__ bk, const float* __restrict__ bv,
             const float* __restrict__ bo, const float* __restrict__ pbias,
             float* __restrict__ out) {
    // 272-byte row stride (17*16) => b128 fragment reads hit all 32 banks uniformly
    __shared__ __align__(16) f16 Wsl[3][16][136];    // W^T head slices (q,k,v)   13056 B
    __shared__ __align__(16) f16 WoT2[128][32];      // Wo^T slice for head pair   8192 B
    __shared__ __align__(16) f16 Qh[80][16];         //                            2560 B
    __shared__ __align__(16) f16 Kh[80][16];
    __shared__ __align__(16) f16 Vh[80][16];
    __shared__ __align__(16) f16 AOl[80][32];        // attn out for head pair     5120 B
    __shared__ float pb_l[200];                      // pbias [8][5][5]
    __shared__ float bo_l[128];
    __shared__ float biasl[3][16];

    const int tid  = threadIdx.x;
    const int wave = tid >> 6;       // 0..4  -> row-tile
    const int lane = tid & 63;
    const int c    = lane & 15;      // MFMA "16-lane" index
    const int g    = lane >> 4;      // MFMA K-group / row-group
    const int token0 = blockIdx.x * 80;

    if (tid < 200) pb_l[tid] = pbias[tid];
    if (tid < 128) bo_l[tid] = bo[tid];

    // ---- A fragments: X rows for this wave's row-tile, loaded once, kept in regs ----
    // A layout (16x16x32): row = lane&15, k = (lane>>4)*8 + j
    f16x8 afrag[4];
    {
        int arow = token0 + wave * 16 + c;
        const float* xr = x + (size_t)arow * 128 + g * 8;
#pragma unroll
        for (int ks = 0; ks < 4; ++ks) {
            const float* p = xr + ks * 32;
            float4 u0 = *(const float4*)(p);
            float4 u1 = *(const float4*)(p + 4);
            f16x8 a;
            a[0] = (f16)u0.x; a[1] = (f16)u0.y; a[2] = (f16)u0.z; a[3] = (f16)u0.w;
            a[4] = (f16)u1.x; a[5] = (f16)u1.y; a[6] = (f16)u1.z; a[7] = (f16)u1.w;
            afrag[ks] = a;
        }
    }

    f32x4 outacc[8];
#pragma unroll
    for (int i = 0; i < 8; ++i) outacc[i] = (f32x4){0.f, 0.f, 0.f, 0.f};

    for (int h = 0; h < NH; ++h) {
        // ---- stage W^T head slices (3 * 16 rows * 128 f16 = 768 * 16B) ----
        for (int u = tid; u < 768; u += 320) {
            int m = u >> 8, r = u & 255, c2 = r >> 4, part = r & 15;
            uint4 val = *(const uint4*)&g_WT[m][16 * h + c2][part * 8];
            *(uint4*)&Wsl[m][c2][part * 8] = val;
        }
        if (tid < 48) {
            const float* bsrc = (tid < 16) ? bq : (tid < 32) ? bk : bv;
            biasl[tid >> 4][tid & 15] = bsrc[16 * h + (tid & 15)];
        }
        __syncthreads();

        // ---- Q,K,V projection for this head: 12 MFMA per wave ----
        f32x4 qa = {0, 0, 0, 0}, ka = {0, 0, 0, 0}, va = {0, 0, 0, 0};
#pragma unroll
        for (int ks = 0; ks < 4; ++ks) {
            int off = ks * 32 + g * 8;
            f16x8 wq = *(const f16x8*)&Wsl[0][c][off];
            f16x8 wk = *(const f16x8*)&Wsl[1][c][off];
            f16x8 wv = *(const f16x8*)&Wsl[2][c][off];
            qa = __builtin_amdgcn_mfma_f32_16x16x32_f16(afrag[ks], wq, qa, 0, 0, 0);
            ka = __builtin_amdgcn_mfma_f32_16x16x32_f16(afrag[ks], wk, ka, 0, 0, 0);
            va = __builtin_amdgcn_mfma_f32_16x16x32_f16(afrag[ks], wv, va, 0, 0, 0);
        }
        {
            // C layout: col = lane&15, row = (lane>>4)*4 + r
            int r0 = wave * 16 + g * 4;
            float bqv = biasl[0][c], bkv = biasl[1][c], bvv = biasl[2][c];
#pragma unroll
            for (int r = 0; r < 4; ++r) {
                Qh[r0 + r][c] = (f16)(qa[r] + bqv);
                Kh[r0 + r][c] = (f16)(ka[r] + bkv);
                Vh[r0 + r][c] = (f16)(va[r] + bvv);
            }
        }
        __syncthreads();

        // ---- attention: 4 threads per token row (80 rows * 4 = 320) ----
        {
            int row = tid >> 2, dq = tid & 3;
            int bl = row / 5;
            int qi = row - bl * 5;
            f16x4 qv = *(const f16x4*)&Qh[row][dq * 4];
            float q0 = (float)qv[0], q1 = (float)qv[1], q2 = (float)qv[2], q3 = (float)qv[3];
            float s[5];
#pragma unroll
            for (int j = 0; j < 5; ++j) {
                f16x4 kv = *(const f16x4*)&Kh[bl * 5 + j][dq * 4];
                float part = q0 * (float)kv[0] + q1 * (float)kv[1] +
                             q2 * (float)kv[2] + q3 * (float)kv[3];
                part += __shfl_xor(part, 1);
                part += __shfl_xor(part, 2);
                s[j] = 0.25f * part + pb_l[h * 25 + qi * 5 + j];
            }
            float mx = fmaxf(fmaxf(fmaxf(s[0], s[1]), fmaxf(s[2], s[3])), s[4]);
            float psum = 0.f;
#pragma unroll
            for (int j = 0; j < 5; ++j) { s[j] = __expf(s[j] - mx); psum += s[j]; }
            float inv = 1.0f / psum;
            float o0 = 0, o1 = 0, o2 = 0, o3 = 0;
#pragma unroll
            for (int j = 0; j < 5; ++j) {
                f16x4 vv = *(const f16x4*)&Vh[bl * 5 + j][dq * 4];
                float pj = s[j] * inv;
                o0 += pj * (float)vv[0]; o1 += pj * (float)vv[1];
                o2 += pj * (float)vv[2]; o3 += pj * (float)vv[3];
            }
            f16x4 ov; ov[0] = (f16)o0; ov[1] = (f16)o1; ov[2] = (f16)o2; ov[3] = (f16)o3;
            *(f16x4*)&AOl[row][(h & 1) * 16 + dq * 4] = ov;
        }

        // ---- stage Wo^T slice for the completed head pair ----
        if (h & 1) {
            int h0 = h - 1;
            for (int u = tid; u < 512; u += 320) {
                int n = u >> 2, part = u & 3;
                uint4 val = *(const uint4*)&g_WT[3][n][h0 * 16 + part * 8];
                *(uint4*)&WoT2[n][part * 8] = val;
            }
        }
        __syncthreads();

        // ---- output projection accumulate: K = 32 (two heads), 8 MFMA per wave ----
        if (h & 1) {
            f16x8 af = *(const f16x8*)&AOl[wave * 16 + c][g * 8];
#pragma unroll
            for (int ct = 0; ct < 8; ++ct) {
                f16x8 bf = *(const f16x8*)&WoT2[ct * 16 + c][g * 8];
                outacc[ct] = __builtin_amdgcn_mfma_f32_16x16x32_f16(af, bf, outacc[ct], 0, 0, 0);
            }
        }
    }

    // ---- store: out[token][col] = acc + bo[col] ----
    {
        int r0 = wave * 16 + g * 4;
#pragma unroll
        for (int ct = 0; ct < 8; ++ct) {
            int col = ct * 16 + c;
            float bov = bo_l[col];
#pragma unroll
            for (int r = 0; r < 4; ++r) {
                int gtok = token0 + r0 + r;
                out[(size_t)gtok * 128 + col] = outacc[ct][r] + bov;
            }
        }
    }
}

extern "C" void kernel_launch(void* const* d_in, const int* in_sizes, int n_in,
                              void* d_out, int out_size, void* d_ws, size_t ws_size,
                              hipStream_t stream) {
    const float* x     = (const float*)d_in[0];
    const float* Wq    = (const float*)d_in[1];
    const float* bq    = (const float*)d_in[2];
    const float* Wk    = (const float*)d_in[3];
    const float* bk    = (const float*)d_in[4];
    const float* Wv    = (const float*)d_in[5];
    const float* bv    = (const float*)d_in[6];
    const float* Wo    = (const float*)d_in[7];
    const float* bo    = (const float*)d_in[8];
    const float* pbias = (const float*)d_in[9];
    float* out = (float*)d_out;

    k_wtrans<<<dim3(256), dim3(256), 0, stream>>>(Wq, Wk, Wv, Wo);
    k_fused<<<dim3(NB / 16), dim3(320), 0, stream>>>(x, bq, bk, bv, bo, pbias, out);
}

// Round 3
// 438.436 us; speedup vs baseline: 1.0306x; 1.0306x over previous
//
#include <hip/hip_runtime.h>

typedef _Float16 f16;
typedef _Float16 f16x2 __attribute__((ext_vector_type(2)));
typedef _Float16 f16x4 __attribute__((ext_vector_type(4)));
typedef _Float16 f16x8 __attribute__((ext_vector_type(8)));
typedef float f32x4 __attribute__((ext_vector_type(4)));

#define NB 65536

// Pre-transposed f16 weights: [m][out_col][k], m: 0=Wq 1=Wk 2=Wv 3=Wo
__device__ __align__(16) f16 g_WT[4][128][128];

__global__ void k_wtrans(const float* __restrict__ Wq, const float* __restrict__ Wk,
                         const float* __restrict__ Wv, const float* __restrict__ Wo) {
    int tid = blockIdx.x * 256 + threadIdx.x;   // 65536 threads
    int m = tid >> 14;
    int r = tid & 16383;
    int n = r >> 7;          // output column
    int k = r & 127;         // K index
    const float* W = (m == 0) ? Wq : (m == 1) ? Wk : (m == 2) ? Wv : Wo;
    g_WT[m][n][k] = (f16)W[k * 128 + n];
}

__device__ __forceinline__ f16x2 bc2(unsigned u) {
    union { unsigned u; f16x2 h; } x; x.u = u; return x.h;
}
__device__ __forceinline__ f16x8 cat8(f16x4 lo, f16x4 hi) {
    f16x8 r;
    r[0] = lo[0]; r[1] = lo[1]; r[2] = lo[2]; r[3] = lo[3];
    r[4] = hi[0]; r[5] = hi[1]; r[6] = hi[2]; r[7] = hi[3];
    return r;
}

// 8 waves per block; wave w owns head w for 16 batches (80 token rows = 5 MFMA tiles).
// LDS: QKV f16 [3][8][80][16] with 4-f16-chunk XOR swizzle (slot = chunk ^ ((row>>2)&3)).
// Phase1: QKV proj (swapped MFMA -> lane holds token c, dims g*4..+3 -> b64 LDS writes)
// Phase2: per-wave attention (fdot2 scores, f32 PV), AO overwrites Q region (wave-private)
// Phase3: O-proj (swapped MFMA -> float4 global stores). Only 2 __syncthreads total.
__global__ __launch_bounds__(512, 4)
void k_fused(const float* __restrict__ x, const float* __restrict__ bq,
             const float* __restrict__ bk, const float* __restrict__ bv,
             const float* __restrict__ bo, const float* __restrict__ pbias,
             float* __restrict__ out) {
    __shared__ __align__(16) f16 QKVs[3][8][80][16];
    __shared__ float pb_l[200];

    const int tid  = threadIdx.x;
    const int w    = tid >> 6;      // wave = head
    const int lane = tid & 63;
    const int c    = lane & 15;
    const int g    = lane >> 4;
    const int base = blockIdx.x * 80;
    const int key_c = (c >> 2) & 3;

    if (tid < 200) pb_l[tid] = pbias[tid];

    // Register-cached W fragments (A operand): lane holds W^T row (w*16+c)
    f16x8 wA[3][4];
#pragma unroll
    for (int ks = 0; ks < 4; ++ks) {
        wA[0][ks] = *(const f16x8*)&g_WT[0][w * 16 + c][ks * 32 + g * 8];
        wA[1][ks] = *(const f16x8*)&g_WT[1][w * 16 + c][ks * 32 + g * 8];
        wA[2][ks] = *(const f16x8*)&g_WT[2][w * 16 + c][ks * 32 + g * 8];
    }
    float4 bq4 = *(const float4*)&bq[w * 16 + g * 4];
    float4 bk4 = *(const float4*)&bk[w * 16 + g * 4];
    float4 bv4 = *(const float4*)&bv[w * 16 + g * 4];

    // ---- Phase 1: QKV projection ----
#pragma unroll 1
    for (int t = 0; t < 5; ++t) {
        const float* xr = x + (size_t)(base + t * 16 + c) * 128;
        f32x4 qa = {0.f, 0.f, 0.f, 0.f}, ka = {0.f, 0.f, 0.f, 0.f}, va = {0.f, 0.f, 0.f, 0.f};
#pragma unroll
        for (int ks = 0; ks < 4; ++ks) {
            float4 u0 = *(const float4*)(xr + ks * 32 + g * 8);
            float4 u1 = *(const float4*)(xr + ks * 32 + g * 8 + 4);
            f16x8 bx;
            bx[0] = (f16)u0.x; bx[1] = (f16)u0.y; bx[2] = (f16)u0.z; bx[3] = (f16)u0.w;
            bx[4] = (f16)u1.x; bx[5] = (f16)u1.y; bx[6] = (f16)u1.z; bx[7] = (f16)u1.w;
            qa = __builtin_amdgcn_mfma_f32_16x16x32_f16(wA[0][ks], bx, qa, 0, 0, 0);
            ka = __builtin_amdgcn_mfma_f32_16x16x32_f16(wA[1][ks], bx, ka, 0, 0, 0);
            va = __builtin_amdgcn_mfma_f32_16x16x32_f16(wA[2][ks], bx, va, 0, 0, 0);
        }
        int row  = t * 16 + c;               // token row; (row>>2)&3 == key_c
        int slot = g ^ key_c;                // swizzled chunk slot
        f16x4 qh, kh, vh;
        qh[0] = (f16)(qa[0] + bq4.x); qh[1] = (f16)(qa[1] + bq4.y);
        qh[2] = (f16)(qa[2] + bq4.z); qh[3] = (f16)(qa[3] + bq4.w);
        kh[0] = (f16)(ka[0] + bk4.x); kh[1] = (f16)(ka[1] + bk4.y);
        kh[2] = (f16)(ka[2] + bk4.z); kh[3] = (f16)(ka[3] + bk4.w);
        vh[0] = (f16)(va[0] + bv4.x); vh[1] = (f16)(va[1] + bv4.y);
        vh[2] = (f16)(va[2] + bv4.z); vh[3] = (f16)(va[3] + bv4.w);
        *(f16x4*)&QKVs[0][w][row][slot * 4] = qh;
        *(f16x4*)&QKVs[1][w][row][slot * 4] = kh;
        *(f16x4*)&QKVs[2][w][row][slot * 4] = vh;
    }
    __syncthreads();

    // ---- Phase 2: attention (wave-private; head w, 80 tasks over 64 lanes) ----
#pragma unroll 1
    for (int pass = 0; pass < 2; ++pass) {
        int task = lane + pass * 64;
        if (task < 80) {
            int row = task;
            int b5  = row / 5;
            int qi  = row - b5 * 5;
            int kr0 = b5 * 5;
            int key = (row >> 2) & 3;

            uint2 qw0 = *(const uint2*)&QKVs[0][w][row][(0 ^ key) * 4];
            uint2 qw1 = *(const uint2*)&QKVs[0][w][row][(1 ^ key) * 4];
            uint2 qw2 = *(const uint2*)&QKVs[0][w][row][(2 ^ key) * 4];
            uint2 qw3 = *(const uint2*)&QKVs[0][w][row][(3 ^ key) * 4];
            f16x2 q0 = bc2(qw0.x), q1 = bc2(qw0.y), q2 = bc2(qw1.x), q3 = bc2(qw1.y);
            f16x2 q4 = bc2(qw2.x), q5 = bc2(qw2.y), q6 = bc2(qw3.x), q7 = bc2(qw3.y);

            float s[5];
#pragma unroll
            for (int j = 0; j < 5; ++j) {
                int kr = kr0 + j;
                int kk = (kr >> 2) & 3;
                uint2 k0 = *(const uint2*)&QKVs[1][w][kr][(0 ^ kk) * 4];
                uint2 k1 = *(const uint2*)&QKVs[1][w][kr][(1 ^ kk) * 4];
                uint2 k2 = *(const uint2*)&QKVs[1][w][kr][(2 ^ kk) * 4];
                uint2 k3 = *(const uint2*)&QKVs[1][w][kr][(3 ^ kk) * 4];
                float d = 0.f;
                d = __builtin_amdgcn_fdot2(q0, bc2(k0.x), d, false);
                d = __builtin_amdgcn_fdot2(q1, bc2(k0.y), d, false);
                d = __builtin_amdgcn_fdot2(q2, bc2(k1.x), d, false);
                d = __builtin_amdgcn_fdot2(q3, bc2(k1.y), d, false);
                d = __builtin_amdgcn_fdot2(q4, bc2(k2.x), d, false);
                d = __builtin_amdgcn_fdot2(q5, bc2(k2.y), d, false);
                d = __builtin_amdgcn_fdot2(q6, bc2(k3.x), d, false);
                d = __builtin_amdgcn_fdot2(q7, bc2(k3.y), d, false);
                s[j] = d * 0.25f + pb_l[w * 25 + qi * 5 + j];
            }
            float mx = fmaxf(fmaxf(fmaxf(s[0], s[1]), fmaxf(s[2], s[3])), s[4]);
            float psum = 0.f;
#pragma unroll
            for (int j = 0; j < 5; ++j) { s[j] = __expf(s[j] - mx); psum += s[j]; }
            float inv = 1.0f / psum;

            float o[16];
#pragma unroll
            for (int i = 0; i < 16; ++i) o[i] = 0.f;
#pragma unroll
            for (int j = 0; j < 5; ++j) {
                int kr = kr0 + j;
                int kk = (kr >> 2) & 3;
                uint2 v0 = *(const uint2*)&QKVs[2][w][kr][(0 ^ kk) * 4];
                uint2 v1 = *(const uint2*)&QKVs[2][w][kr][(1 ^ kk) * 4];
                uint2 v2 = *(const uint2*)&QKVs[2][w][kr][(2 ^ kk) * 4];
                uint2 v3 = *(const uint2*)&QKVs[2][w][kr][(3 ^ kk) * 4];
                float p = s[j] * inv;
                f16x2 a;
                a = bc2(v0.x); o[0]  += p * (float)a[0]; o[1]  += p * (float)a[1];
                a = bc2(v0.y); o[2]  += p * (float)a[0]; o[3]  += p * (float)a[1];
                a = bc2(v1.x); o[4]  += p * (float)a[0]; o[5]  += p * (float)a[1];
                a = bc2(v1.y); o[6]  += p * (float)a[0]; o[7]  += p * (float)a[1];
                a = bc2(v2.x); o[8]  += p * (float)a[0]; o[9]  += p * (float)a[1];
                a = bc2(v2.y); o[10] += p * (float)a[0]; o[11] += p * (float)a[1];
                a = bc2(v3.x); o[12] += p * (float)a[0]; o[13] += p * (float)a[1];
                a = bc2(v3.y); o[14] += p * (float)a[0]; o[15] += p * (float)a[1];
            }
            // AO overwrites Q region (wave-private; pass-1 rows never re-read)
            f16x4 oc;
            oc[0] = (f16)o[0];  oc[1] = (f16)o[1];  oc[2] = (f16)o[2];  oc[3] = (f16)o[3];
            *(f16x4*)&QKVs[0][w][row][(0 ^ key) * 4] = oc;
            oc[0] = (f16)o[4];  oc[1] = (f16)o[5];  oc[2] = (f16)o[6];  oc[3] = (f16)o[7];
            *(f16x4*)&QKVs[0][w][row][(1 ^ key) * 4] = oc;
            oc[0] = (f16)o[8];  oc[1] = (f16)o[9];  oc[2] = (f16)o[10]; oc[3] = (f16)o[11];
            *(f16x4*)&QKVs[0][w][row][(2 ^ key) * 4] = oc;
            oc[0] = (f16)o[12]; oc[1] = (f16)o[13]; oc[2] = (f16)o[14]; oc[3] = (f16)o[15];
            *(f16x4*)&QKVs[0][w][row][(3 ^ key) * 4] = oc;
        }
    }
    __syncthreads();

    // ---- Phase 3: output projection (wave w -> output cols w*16..w*16+15) ----
    f16x8 wo[4];
#pragma unroll
    for (int ks = 0; ks < 4; ++ks)
        wo[ks] = *(const f16x8*)&g_WT[3][w * 16 + c][ks * 32 + g * 8];
    float4 bo4 = *(const float4*)&bo[w * 16 + g * 4];
    const int hh_b = g >> 1;
    const int c0   = (g & 1) * 2;
#pragma unroll 1
    for (int t = 0; t < 5; ++t) {
        int row = t * 16 + c;                 // (row>>2)&3 == key_c
        f32x4 acc = {0.f, 0.f, 0.f, 0.f};
#pragma unroll
        for (int ks = 0; ks < 4; ++ks) {
            int hh = ks * 2 + hh_b;
            f16x4 lo = *(const f16x4*)&QKVs[0][hh][row][((c0 ^ key_c)) * 4];
            f16x4 hi = *(const f16x4*)&QKVs[0][hh][row][(((c0 + 1) ^ key_c)) * 4];
            acc = __builtin_amdgcn_mfma_f32_16x16x32_f16(wo[ks], cat8(lo, hi), acc, 0, 0, 0);
        }
        float4 r;
        r.x = acc[0] + bo4.x; r.y = acc[1] + bo4.y;
        r.z = acc[2] + bo4.z; r.w = acc[3] + bo4.w;
        *(float4*)&out[(size_t)(base + row) * 128 + w * 16 + g * 4] = r;
    }
}

extern "C" void kernel_launch(void* const* d_in, const int* in_sizes, int n_in,
                              void* d_out, int out_size, void* d_ws, size_t ws_size,
                              hipStream_t stream) {
    const float* x     = (const float*)d_in[0];
    const float* Wq    = (const float*)d_in[1];
    const float* bq    = (const float*)d_in[2];
    const float* Wk    = (const float*)d_in[3];
    const float* bk    = (const float*)d_in[4];
    const float* Wv    = (const float*)d_in[5];
    const float* bv    = (const float*)d_in[6];
    const float* Wo    = (const float*)d_in[7];
    const float* bo    = (const float*)d_in[8];
    const float* pbias = (const float*)d_in[9];
    float* out = (float*)d_out;

    k_wtrans<<<dim3(256), dim3(256), 0, stream>>>(Wq, Wk, Wv, Wo);
    k_fused<<<dim3(NB / 16), dim3(512), 0, stream>>>(x, bq, bk, bv, bo, pbias, out);
}